// Round 7
// baseline (2571.875 us; speedup 1.0000x reference)
//
#include <hip/hip_runtime.h>
#include <hip/hip_fp16.h>
#include <cstdint>

#define NLAYERS 4
#define TILE_E 32
#define MS_NODES 4

__device__ __forceinline__ float silu_f(float x){ return x / (1.f + __expf(-x)); }

// ---------------- init ----------------
__global__ void k_init(const int* __restrict__ z, const float* __restrict__ embed,
                       float* __restrict__ hs, float* __restrict__ hv, float* __restrict__ ht,
                       int* __restrict__ deg,
                       unsigned* __restrict__ mkey, float* __restrict__ den, float* __restrict__ cbuf,
                       int N, int G){
  int idx = blockIdx.x*blockDim.x + threadIdx.x;
  if (idx < N*64) hs[idx] = embed[z[idx>>6]*64 + (idx&63)];
  if (idx < N*96) hv[idx] = 0.f;
  if (idx < N*80) ht[idx] = 0.f;
  if (idx < N)   deg[idx] = 0;
  if (idx < G) { mkey[idx] = 0u; den[idx] = 0.f; }
  if (idx < G*64) cbuf[idx] = 0.f;
}

// ---------------- weight transpose (once per launch) ----------------
// per-layer layout (17920 floats):
//  0     WsT  [f64][cc112]
//  7168  WssT [f64][cc64]
//  11264 WvT  [f32][cc128]
//  15360 WvvT [f32][cc32]
//  16384 WtT  [f16][cc80]
//  17664 WttT [f16][cc16]
__global__ void k_prep(const float* __restrict__ Ws, const float* __restrict__ Wss,
                       const float* __restrict__ Wv, const float* __restrict__ Wvv,
                       const float* __restrict__ Wt, const float* __restrict__ Wtt,
                       float* __restrict__ wT){
  int idx = blockIdx.x*256 + threadIdx.x;
  if (idx >= NLAYERS*17920) return;
  int l = idx / 17920, r = idx - l*17920;
  float v;
  if (r < 7168){ int f=r/112, cc=r-f*112; v = Ws[((size_t)l*112+cc)*64+f]; }
  else if (r < 11264){ int q=r-7168; int f=q>>6, cc=q&63; v = Wss[((size_t)l*64+cc)*64+f]; }
  else if (r < 15360){ int q=r-11264; int f=q>>7, cc=q&127; v = Wv[((size_t)l*128+cc)*32+f]; }
  else if (r < 16384){ int q=r-15360; int f=q>>5, cc=q&31; v = Wvv[((size_t)l*32+cc)*32+f]; }
  else if (r < 17664){ int q=r-16384; int f=q/80, cc=q-f*80; v = Wt[((size_t)l*80+cc)*16+f]; }
  else { int q=r-17664; int f=q>>4, cc=q&15; v = Wtt[((size_t)l*16+cc)*16+f]; }
  wT[(size_t)l*17920 + r] = v;
}

// ---------------- CSR build ----------------
__global__ void k_deg(const int* __restrict__ dst, int* __restrict__ deg, int E){
  int e = blockIdx.x*blockDim.x + threadIdx.x;
  if (e < E) atomicAdd(&deg[dst[e]], 1);
}

__global__ __launch_bounds__(256) void k_scanA(const int* __restrict__ deg, int* __restrict__ bsum, int N){
  __shared__ int red[256];
  int t = threadIdx.x;
  int idx = blockIdx.x*256 + t;
  red[t] = (idx < N) ? deg[idx] : 0;
  __syncthreads();
  for (int off=128; off>0; off>>=1){ if (t<off) red[t] += red[t+off]; __syncthreads(); }
  if (t==0) bsum[blockIdx.x] = red[0];
}

__global__ __launch_bounds__(256) void k_scanB(const int* __restrict__ bsum, int* __restrict__ boff, int nb){
  __shared__ int s[256];
  int t = threadIdx.x;
  s[t] = (t < nb) ? bsum[t] : 0;
  __syncthreads();
  for (int off=1; off<256; off<<=1){
    int v = (t>=off) ? s[t-off] : 0;
    __syncthreads();
    s[t] += v;
    __syncthreads();
  }
  if (t < nb) boff[t] = (t==0) ? 0 : s[t-1];
}

__global__ __launch_bounds__(256) void k_scanC(const int* __restrict__ deg, const int* __restrict__ boff,
                                               int* __restrict__ rowptr, int* __restrict__ cursor, int N){
  __shared__ int s[256];
  int t = threadIdx.x;
  int idx = blockIdx.x*256 + t;
  int v = (idx < N) ? deg[idx] : 0;
  s[t] = v;
  __syncthreads();
  for (int off=1; off<256; off<<=1){
    int u = (t>=off) ? s[t-off] : 0;
    __syncthreads();
    s[t] += u;
    __syncthreads();
  }
  int base = boff[blockIdx.x];
  if (idx < N){
    int ex = base + s[t] - v;
    rowptr[idx] = ex;
    cursor[idx] = ex;
    if (idx == N-1) rowptr[N] = base + s[t];
  }
}

__global__ void k_fill(const int* __restrict__ dst, const int* __restrict__ src,
                       int* __restrict__ cursor, int* __restrict__ inv, int* __restrict__ src_sorted, int E){
  int e = blockIdx.x*blockDim.x + threadIdx.x;
  if (e < E){
    int p = atomicAdd(&cursor[dst[e]], 1);
    inv[e] = p;
    src_sorted[p] = src[e];
  }
}

// ---------------- edge features in CSR order ----------------
__global__ void k_efeat(const float* __restrict__ pos, const int* __restrict__ src,
                        const int* __restrict__ dst, const int* __restrict__ inv,
                        float* __restrict__ rb_csr, float* __restrict__ y_csr, int E){
  int e = blockIdx.x*blockDim.x + threadIdx.x;
  if (e >= E) return;
  int s = src[e], d = dst[e];
  int j = inv[e];
  float vx = pos[d*3+0]-pos[s*3+0];
  float vy = pos[d*3+1]-pos[s*3+1];
  float vz = pos[d*3+2]-pos[s*3+2];
  float elen = sqrtf(vx*vx+vy*vy+vz*vz);
  float iv = 1.f/(elen+1e-9f);
  float x = vx*iv, y = vy*iv, zc = vz*iv;
  const float s3 = 1.7320508075688772f, s5 = 2.2360679774997896f, s15 = 3.872983346207417f;
  float* yp = y_csr + (size_t)j*8;   // Y1..Y8 (Y0==1 implicit)
  yp[0] = s3*x;  yp[1] = s3*y;  yp[2] = s3*zc;
  yp[3] = s15*x*y; yp[4] = s15*y*zc;
  yp[5] = 0.5f*s5*(3.f*zc*zc-1.f);
  yp[6] = s15*x*zc; yp[7] = 0.5f*s15*(x*x-y*y);
  const float sigma = 5.0f/9.0f;
  float* rp = rb_csr + (size_t)j*10;
  #pragma unroll
  for (int k=0;k<10;k++){
    float c = (5.0f/9.0f)*(float)k;
    float tt = (elen - c)/sigma;
    rp[k] = __expf(-0.5f*tt*tt);
  }
}

// ---------------- k_wgt: radial weights in CSR order, fp16 ----------------
__global__ __launch_bounds__(320) void k_wgt(
    const float* __restrict__ rb_csr,
    const float* __restrict__ rW1, const float* __restrict__ rb1, const float* __restrict__ rW2,
    __half* __restrict__ wgtbuf, int E, int l)
{
  __shared__ float hid[TILE_E][32];
  int t = threadIdx.x;
  int j0 = blockIdx.x*TILE_E;

  for (int idx=t; idx<TILE_E*32; idx+=320){
    int el = idx>>5, jj = idx&31;
    int j = j0+el;
    if (j < E){
      float acc = rb1[l*32+jj];
      const float* rbp = rb_csr + (size_t)j*10;
      const float* w1p = rW1 + (l*10)*32 + jj;
      #pragma unroll
      for (int k=0;k<10;k++) acc += rbp[k]*w1p[k*32];
      hid[el][jj] = silu_f(acc);
    }
  }
  float wcol[32];
  {
    const float* w2p = rW2 + (size_t)(l*32)*320 + t;
    #pragma unroll
    for (int jj=0;jj<32;jj++) wcol[jj] = w2p[(size_t)jj*320];
  }
  __syncthreads();

  for (int el=0; el<TILE_E; el++){
    int j = j0+el;
    if (j >= E) break;
    const float4* hrow = (const float4*)hid[el];
    float a0=0.f,a1=0.f,a2=0.f,a3=0.f;
    #pragma unroll
    for (int q=0;q<8;q++){
      float4 h4 = hrow[q];
      a0 += h4.x*wcol[q*4+0];
      a1 += h4.y*wcol[q*4+1];
      a2 += h4.z*wcol[q*4+2];
      a3 += h4.w*wcol[q*4+3];
    }
    wgtbuf[(size_t)j*320 + t] = __float2half((a0+a1)+(a2+a3));
  }
}

// ---------------- k_msg: wave-per-edge LDS-atomic accumulate + fused update ----------------
// padded comp layout per node (1152): [0,128) a0 (112 real);
//   [128,512) a1 dd-major: 128+dd*128+row (row<128: 64 scalar,32 vec,32 cross);
//   [512,1152) a2 dd-major: 512+dd*128+row (row<80: 64 scalar,16 tensor)
// hold layout per node (240): [0,64) s; [64,160) v as 64+dd*32+row; [160,240) t as 160+dd*16+row
__global__ __launch_bounds__(256, 4) void k_msg(
    const float* __restrict__ hs0, const float* __restrict__ hv0, const float* __restrict__ ht0,
    float* __restrict__ hs1, float* __restrict__ hv1, float* __restrict__ ht1,
    const int* __restrict__ rowptr, const int* __restrict__ src_sorted,
    const float* __restrict__ y_csr, const __half* __restrict__ wgtbuf,
    const float* __restrict__ wT, int N, int l)
{
  __shared__ float accL[MS_NODES][1152];
  __shared__ float hold[MS_NODES][240];
  int t = threadIdx.x, w = t>>6, lane = t&63;
  int n0 = blockIdx.x*MS_NODES;
  int nmax = min(MS_NODES, N-n0);

  for (int i=t; i<MS_NODES*1152; i+=256) (&accL[0][0])[i] = 0.f;
  for (int idx=t; idx<nmax*240; idx+=256){
    int n = idx/240, c = idx - n*240;
    float v; int dstc;
    if (c < 64){ v = hs0[(size_t)(n0+n)*64 + c]; dstc = c; }
    else if (c < 160){ int cc=c-64; v = hv0[(size_t)(n0+n)*96 + cc]; int row=cc/3, dd=cc-row*3; dstc = 64+dd*32+row; }
    else { int cc=c-160; v = ht0[(size_t)(n0+n)*80 + cc]; int row=cc/5, dd=cc-row*5; dstc = 160+dd*16+row; }
    hold[n][dstc] = v;
  }
  __syncthreads();   // accL must be fully zeroed before any wave's atomics (R6 bug fix)

  int rw[MS_NODES+1];
  #pragma unroll
  for (int i=0;i<=MS_NODES;i++) rw[i] = rowptr[min(n0+i, N)];
  int rs = rw[0], re = rw[MS_NODES];

  for (int j = rs + w; j < re; j += 4){
    int slot = 0;
    #pragma unroll
    for (int i=1;i<MS_NODES;i++) slot += (j >= rw[i]);
    int s_ = src_sorted[j];
    const float* pS = hs0 + (size_t)s_*64;
    const float* pV = hv0 + (size_t)s_*96;
    const float* pT = ht0 + (size_t)s_*80;
    const __half* wp = wgtbuf + (size_t)j*320;
    const float* yp = y_csr + (size_t)j*8;
    float y0=yp[0],y1=yp[1],y2=yp[2],y3=yp[3],y4=yp[4],y5=yp[5],y6=yp[6],y7=yp[7];
    float* base = &accL[slot][0];
    float sL = pS[lane];
    float w0 = __half2float(wp[lane]);
    float w1 = (lane<48) ? __half2float(wp[64+lane]) : 0.f;
    float wA = __half2float(wp[112+lane]);
    float wB = __half2float(wp[176+lane]);
    float wC = __half2float(wp[240+lane]);
    float wD = (lane<16) ? __half2float(wp[304+lane]) : 0.f;

    // a0
    atomicAdd(base+lane, w0*sL);
    if (lane < 32){
      float d3 = pV[lane*3+0]*y0 + pV[lane*3+1]*y1 + pV[lane*3+2]*y2;
      atomicAdd(base+64+lane, w1*d3);
    } else if (lane < 48){
      int cc = lane-32;
      float d5 = pT[cc*5+0]*y3 + pT[cc*5+1]*y4 + pT[cc*5+2]*y5 + pT[cc*5+3]*y6 + pT[cc*5+4]*y7;
      atomicAdd(base+64+lane, w1*d5);
    }
    // a1 dd=0,1,2
    {
      float gb0, gb1, gb2;
      if (lane < 32){
        gb0 = wB * pV[lane*3+0];
        gb1 = wB * pV[lane*3+1];
        gb2 = wB * pV[lane*3+2];
      } else {
        int rr = lane-32;
        float vx = pV[rr*3+0], vy = pV[rr*3+1], vz = pV[rr*3+2];
        gb0 = wB * (vy*y2 - vz*y1);
        gb1 = wB * (vz*y0 - vx*y2);
        gb2 = wB * (vx*y1 - vy*y0);
      }
      atomicAdd(base+128+lane,     wA*sL*y0);
      atomicAdd(base+128+64+lane,  gb0);
      atomicAdd(base+256+lane,     wA*sL*y1);
      atomicAdd(base+256+64+lane,  gb1);
      atomicAdd(base+384+lane,     wA*sL*y2);
      atomicAdd(base+384+64+lane,  gb2);
    }
    // a2 dd=0..4
    {
      float t0=0.f,t1=0.f,t2=0.f,t3=0.f,t4=0.f;
      if (lane < 16){
        t0 = wD*pT[lane*5+0]; t1 = wD*pT[lane*5+1]; t2 = wD*pT[lane*5+2];
        t3 = wD*pT[lane*5+3]; t4 = wD*pT[lane*5+4];
      }
      atomicAdd(base+512+lane,  wC*sL*y3);
      atomicAdd(base+640+lane,  wC*sL*y4);
      atomicAdd(base+768+lane,  wC*sL*y5);
      atomicAdd(base+896+lane,  wC*sL*y6);
      atomicAdd(base+1024+lane, wC*sL*y7);
      if (lane < 16){
        atomicAdd(base+512+64+lane,  t0);
        atomicAdd(base+640+64+lane,  t1);
        atomicAdd(base+768+64+lane,  t2);
        atomicAdd(base+896+64+lane,  t3);
        atomicAdd(base+1024+64+lane, t4);
      }
    }
  }
  __syncthreads();

  // ---- phase 2: fused dense update with transposed streaming weights ----
  const float* wTl = wT + (size_t)l*17920;
  if (t < 64){
    int f = t;
    float ua[MS_NODES] = {0.f,0.f,0.f,0.f};
    const float* wr = wTl + f*112;
    for (int c=0;c<112;c+=4){
      float4 w4 = *(const float4*)(wr+c);
      #pragma unroll
      for (int nn=0;nn<MS_NODES;nn++){
        float4 a4 = *(const float4*)(&accL[nn][c]);
        ua[nn] += a4.x*w4.x + a4.y*w4.y + a4.z*w4.z + a4.w*w4.w;
      }
    }
    const float* wr2 = wTl + 7168 + f*64;
    for (int c=0;c<64;c+=4){
      float4 w4 = *(const float4*)(wr2+c);
      #pragma unroll
      for (int nn=0;nn<MS_NODES;nn++){
        float4 h4 = *(const float4*)(&hold[nn][c]);
        ua[nn] += h4.x*w4.x + h4.y*w4.y + h4.z*w4.z + h4.w*w4.w;
      }
    }
    for (int nn=0;nn<nmax;nn++) hs1[(size_t)(n0+nn)*64+f] = silu_f(ua[nn]);
  } else if (t < 160){
    int rr = t-64, f = rr&31, dd = rr>>5;
    float ua[MS_NODES] = {0.f,0.f,0.f,0.f};
    const float* wr = wTl + 11264 + f*128;
    for (int c=0;c<128;c+=4){
      float4 w4 = *(const float4*)(wr+c);
      #pragma unroll
      for (int nn=0;nn<MS_NODES;nn++){
        float4 a4 = *(const float4*)(&accL[nn][128+dd*128+c]);
        ua[nn] += a4.x*w4.x + a4.y*w4.y + a4.z*w4.z + a4.w*w4.w;
      }
    }
    const float* wr2 = wTl + 15360 + f*32;
    for (int c=0;c<32;c+=4){
      float4 w4 = *(const float4*)(wr2+c);
      #pragma unroll
      for (int nn=0;nn<MS_NODES;nn++){
        float4 h4 = *(const float4*)(&hold[nn][64+dd*32+c]);
        ua[nn] += h4.x*w4.x + h4.y*w4.y + h4.z*w4.z + h4.w*w4.w;
      }
    }
    for (int nn=0;nn<nmax;nn++) hv1[(size_t)(n0+nn)*96 + f*3 + dd] = ua[nn];
  } else if (t < 240){
    int rr = t-160, f = rr&15, dd = rr>>4;
    float ua[MS_NODES] = {0.f,0.f,0.f,0.f};
    const float* wr = wTl + 16384 + f*80;
    for (int c=0;c<80;c+=4){
      float4 w4 = *(const float4*)(wr+c);
      #pragma unroll
      for (int nn=0;nn<MS_NODES;nn++){
        float4 a4 = *(const float4*)(&accL[nn][512+dd*128+c]);
        ua[nn] += a4.x*w4.x + a4.y*w4.y + a4.z*w4.z + a4.w*w4.w;
      }
    }
    const float* wr2 = wTl + 17664 + f*16;
    for (int c=0;c<16;c+=4){
      float4 w4 = *(const float4*)(wr2+c);
      #pragma unroll
      for (int nn=0;nn<MS_NODES;nn++){
        float4 h4 = *(const float4*)(&hold[nn][160+dd*16+c]);
        ua[nn] += h4.x*w4.x + h4.y*w4.y + h4.z*w4.z + h4.w*w4.w;
      }
    }
    for (int nn=0;nn<nmax;nn++) ht1[(size_t)(n0+nn)*80 + f*5 + dd] = ua[nn];
  }
}

// ---------------- readout ----------------
__global__ __launch_bounds__(64) void k_q(const float* __restrict__ hs, const int* __restrict__ absorber,
                                          const float* __restrict__ Wq, float* __restrict__ qbuf, int G){
  __shared__ float sH[64];
  int g = blockIdx.x, f = threadIdx.x;
  int a = absorber[g];
  sH[f] = hs[(size_t)a*64+f];
  __syncthreads();
  float acc = 0.f;
  for (int c=0;c<64;c++) acc += sH[c]*Wq[c*64+f];
  qbuf[(size_t)g*64+f] = acc;
}

__global__ __launch_bounds__(64) void k_kv(const float* __restrict__ hs,
                                           const float* __restrict__ Wk, const float* __restrict__ Wvp,
                                           float* __restrict__ kbuf, float* __restrict__ vbuf, int N){
  __shared__ float sH[8][64];
  int t = threadIdx.x;
  int n0 = blockIdx.x*8;
  int nmax = min(8, N-n0);
  for (int idx=t; idx<nmax*64; idx+=64){ int n=idx>>6, c=idx&63; sH[n][c]=hs[(size_t)(n0+n)*64+c]; }
  __syncthreads();
  float ka[8], va[8];
  #pragma unroll
  for (int n=0;n<8;n++){ ka[n]=0.f; va[n]=0.f; }
  for (int c=0;c<64;c++){
    float wk = Wk[c*64+t], wv = Wvp[c*64+t];
    #pragma unroll
    for (int n=0;n<8;n++){ ka[n]+=sH[n][c]*wk; va[n]+=sH[n][c]*wv; }
  }
  for (int n=0;n<nmax;n++){ kbuf[(size_t)(n0+n)*64+t]=ka[n]; vbuf[(size_t)(n0+n)*64+t]=va[n]; }
}

__global__ __launch_bounds__(256) void k_logit(const float* __restrict__ kbuf, const float* __restrict__ qbuf,
                                               const int* __restrict__ batch,
                                               float* __restrict__ logitbuf, unsigned* __restrict__ mkey, int N){
  int wave = threadIdx.x>>6, lane = threadIdx.x&63;
  int n = blockIdx.x*4 + wave;
  if (n >= N) return;
  int g = batch[n];
  float p = kbuf[(size_t)n*64+lane]*qbuf[(size_t)g*64+lane];
  #pragma unroll
  for (int off=32; off>0; off>>=1) p += __shfl_down(p, off, 64);
  if (lane==0){
    float logit = p*0.125f;
    logitbuf[n] = logit;
    unsigned u = __float_as_uint(logit);
    unsigned key = (u & 0x80000000u) ? ~u : (u | 0x80000000u);
    atomicMax(&mkey[g], key);
  }
}

__global__ __launch_bounds__(256) void k_soft(const float* __restrict__ vbuf, const float* __restrict__ logitbuf,
                                              const int* __restrict__ batch, const unsigned* __restrict__ mkey,
                                              float* __restrict__ den, float* __restrict__ cbuf, int N){
  int wave = threadIdx.x>>6, lane = threadIdx.x&63;
  int n = blockIdx.x*4 + wave;
  if (n >= N) return;
  int g = batch[n];
  unsigned key = mkey[g];
  unsigned u = (key & 0x80000000u) ? (key ^ 0x80000000u) : ~key;
  float m = __uint_as_float(u);
  float ex = __expf(logitbuf[n] - m);
  if (lane==0) atomicAdd(&den[g], ex);
  atomicAdd(&cbuf[(size_t)g*64+lane], ex*vbuf[(size_t)n*64+lane]);
}

__global__ __launch_bounds__(192) void k_final(const float* __restrict__ hs, const float* __restrict__ hv,
                                               const float* __restrict__ ht, const int* __restrict__ absorber,
                                               const float* __restrict__ den, const float* __restrict__ cbuf,
                                               const float* __restrict__ Wr1, const float* __restrict__ br1,
                                               const float* __restrict__ Wr2, const float* __restrict__ br2,
                                               float* __restrict__ out, int G){
  __shared__ float zr[176];
  __shared__ float h1[128];
  int g = blockIdx.x, t = threadIdx.x;
  int a = absorber[g];
  if (t < 64) zr[t] = hs[(size_t)a*64+t];
  else if (t < 128){
    int f = t-64;
    zr[t] = cbuf[(size_t)g*64+f] / fmaxf(den[g], 1e-9f);
  } else if (t < 160){
    int j = t-128; float s = 0.f;
    #pragma unroll
    for (int dd=0;dd<3;dd++){ float v = hv[(size_t)a*96+j*3+dd]; s += v*v; }
    zr[t] = s;
  } else if (t < 176){
    int j = t-160; float s = 0.f;
    #pragma unroll
    for (int dd=0;dd<5;dd++){ float v = ht[(size_t)a*80+j*5+dd]; s += v*v; }
    zr[t] = s;
  }
  __syncthreads();
  if (t < 128){
    float acc = br1[t];
    for (int i=0;i<176;i++) acc += zr[i]*Wr1[i*128+t];
    h1[t] = silu_f(acc);
  }
  __syncthreads();
  if (t < 128){
    float acc = br2[t];
    for (int j=0;j<128;j++) acc += h1[j]*Wr2[j*128+t];
    out[(size_t)g*128+t] = acc;
  }
}

extern "C" void kernel_launch(void* const* d_in, const int* in_sizes, int n_in,
                              void* d_out, int out_size, void* d_ws, size_t ws_size,
                              hipStream_t stream){
  const int*   z        = (const int*)  d_in[0];
  const float* pos      = (const float*)d_in[1];
  const int*   ei       = (const int*)  d_in[2];
  const int*   batch    = (const int*)  d_in[3];
  const int*   absorber = (const int*)  d_in[4];
  const float* embed    = (const float*)d_in[5];
  const float* rW1      = (const float*)d_in[6];
  const float* rb1      = (const float*)d_in[7];
  const float* rW2      = (const float*)d_in[8];
  const float* Ws       = (const float*)d_in[9];
  const float* Wss      = (const float*)d_in[10];
  const float* Wv       = (const float*)d_in[11];
  const float* Wvv      = (const float*)d_in[12];
  const float* Wt       = (const float*)d_in[13];
  const float* Wtt      = (const float*)d_in[14];
  const float* Wq       = (const float*)d_in[15];
  const float* Wk       = (const float*)d_in[16];
  const float* Wvp      = (const float*)d_in[17];
  const float* Wr1      = (const float*)d_in[18];
  const float* br1      = (const float*)d_in[19];
  const float* Wr2      = (const float*)d_in[20];
  const float* br2      = (const float*)d_in[21];

  int N = in_sizes[0];
  int E = in_sizes[2]/2;
  int G = in_sizes[4];
  const int* srcArr = ei;
  const int* dstArr = ei + E;

  float* p = (float*)d_ws;
  float* hsA   = p; p += (size_t)N*64;
  float* hvA   = p; p += (size_t)N*96;
  float* htA   = p; p += (size_t)N*80;
  float* hsB   = p; p += (size_t)N*64;
  float* hvB   = p; p += (size_t)N*96;
  float* htB   = p; p += (size_t)N*80;
  float* rb_csr= p; p += (size_t)E*10;
  float* y_csr = p; p += (size_t)E*8;
  unsigned* mkey = (unsigned*)p; p += G;
  float* den   = p; p += G;
  float* cbuf  = p; p += (size_t)G*64;
  int* deg     = (int*)p; p += N;
  int* rowptr  = (int*)p; p += (N+1);
  int* cursor  = (int*)p; p += N;
  int* inv     = (int*)p; p += E;
  int* src_sorted = (int*)p; p += E;
  int* bsum    = (int*)p; p += 256;
  int* boff    = (int*)p; p += 256;
  p += ((8 - (((uintptr_t)p >> 2) & 7)) & 7);   // 32B align
  __half* wgtbuf = (__half*)p; p += (size_t)E*160;   // E*320 halfs
  float* wT     = p; p += (size_t)NLAYERS*17920;
  // readout buffers alias wgtbuf (dead after last k_msg)
  float* kbuf    = (float*)wgtbuf;
  float* vbuf    = kbuf + (size_t)N*64;
  float* qbuf    = vbuf + (size_t)N*64;
  float* logitbuf= qbuf + (size_t)G*64;

  int nb = (N + 255)/256;
  int initTot = N*96;
  k_init<<<(initTot+255)/256, 256, 0, stream>>>(z, embed, hsA, hvA, htA, deg, mkey, den, cbuf, N, G);
  k_prep<<<(NLAYERS*17920+255)/256, 256, 0, stream>>>(Ws, Wss, Wv, Wvv, Wt, Wtt, wT);
  k_deg<<<(E+255)/256, 256, 0, stream>>>(dstArr, deg, E);
  k_scanA<<<nb, 256, 0, stream>>>(deg, bsum, N);
  k_scanB<<<1, 256, 0, stream>>>(bsum, boff, nb);
  k_scanC<<<nb, 256, 0, stream>>>(deg, boff, rowptr, cursor, N);
  k_fill<<<(E+255)/256, 256, 0, stream>>>(dstArr, srcArr, cursor, inv, src_sorted, E);
  k_efeat<<<(E+255)/256, 256, 0, stream>>>(pos, srcArr, dstArr, inv, rb_csr, y_csr, E);

  float *hsO=hsA, *hvO=hvA, *htO=htA, *hsN=hsB, *hvN=hvB, *htN=htB;
  for (int l=0; l<NLAYERS; l++){
    k_wgt<<<(E+TILE_E-1)/TILE_E, 320, 0, stream>>>(rb_csr, rW1, rb1, rW2, wgtbuf, E, l);
    k_msg<<<(N+MS_NODES-1)/MS_NODES, 256, 0, stream>>>(hsO, hvO, htO, hsN, hvN, htN,
                                                       rowptr, src_sorted, y_csr, wgtbuf,
                                                       wT, N, l);
    float* tp;
    tp=hsO; hsO=hsN; hsN=tp;
    tp=hvO; hvO=hvN; hvN=tp;
    tp=htO; htO=htN; htN=tp;
  }

  k_q<<<G, 64, 0, stream>>>(hsO, absorber, Wq, qbuf, G);
  k_kv<<<(N+7)/8, 64, 0, stream>>>(hsO, Wk, Wvp, kbuf, vbuf, N);
  k_logit<<<(N+3)/4, 256, 0, stream>>>(kbuf, qbuf, batch, logitbuf, mkey, N);
  k_soft<<<(N+3)/4, 256, 0, stream>>>(vbuf, logitbuf, batch, mkey, den, cbuf, N);
  k_final<<<G, 192, 0, stream>>>(hsO, hvO, htO, absorber, den, cbuf, Wr1, br1, Wr2, br2, (float*)d_out, G);
}

// Round 8
// 2128.089 us; speedup vs baseline: 1.2085x; 1.2085x over previous
//
#include <hip/hip_runtime.h>
#include <hip/hip_fp16.h>
#include <cstdint>

#define NLAYERS 4
#define TILE_E 32
#define SCAT_K 16
#define UP_NODES 8

__device__ __forceinline__ float silu_f(float x){ return x / (1.f + __expf(-x)); }

// H layout per node (240): [0,64) s, [64,160) v (row*3+dd), [160,240) t (row*5+dd)

// ---------------- init ----------------
__global__ void k_init(const int* __restrict__ z, const float* __restrict__ embed,
                       float* __restrict__ H, int* __restrict__ deg,
                       unsigned* __restrict__ mkey, float* __restrict__ den, float* __restrict__ cbuf,
                       int N, int G){
  int idx = blockIdx.x*blockDim.x + threadIdx.x;
  if (idx < N*240){
    int n = idx/240, c = idx - n*240;
    H[idx] = (c < 64) ? embed[z[n]*64 + c] : 0.f;
  }
  if (idx < N)   deg[idx] = 0;
  if (idx < G) { mkey[idx] = 0u; den[idx] = 0.f; }
  if (idx < G*64) cbuf[idx] = 0.f;
}

// ---------------- CSR build ----------------
__global__ void k_deg(const int* __restrict__ dst, int* __restrict__ deg, int E){
  int e = blockIdx.x*blockDim.x + threadIdx.x;
  if (e < E) atomicAdd(&deg[dst[e]], 1);
}

__global__ __launch_bounds__(256) void k_scanA(const int* __restrict__ deg, int* __restrict__ bsum, int N){
  __shared__ int red[256];
  int t = threadIdx.x;
  int idx = blockIdx.x*256 + t;
  red[t] = (idx < N) ? deg[idx] : 0;
  __syncthreads();
  for (int off=128; off>0; off>>=1){ if (t<off) red[t] += red[t+off]; __syncthreads(); }
  if (t==0) bsum[blockIdx.x] = red[0];
}

__global__ __launch_bounds__(256) void k_scanB(const int* __restrict__ bsum, int* __restrict__ boff, int nb){
  __shared__ int s[256];
  int t = threadIdx.x;
  s[t] = (t < nb) ? bsum[t] : 0;
  __syncthreads();
  for (int off=1; off<256; off<<=1){
    int v = (t>=off) ? s[t-off] : 0;
    __syncthreads();
    s[t] += v;
    __syncthreads();
  }
  if (t < nb) boff[t] = (t==0) ? 0 : s[t-1];
}

__global__ __launch_bounds__(256) void k_scanC(const int* __restrict__ deg, const int* __restrict__ boff,
                                               int* __restrict__ rowptr, int* __restrict__ cursor, int N){
  __shared__ int s[256];
  int t = threadIdx.x;
  int idx = blockIdx.x*256 + t;
  int v = (idx < N) ? deg[idx] : 0;
  s[t] = v;
  __syncthreads();
  for (int off=1; off<256; off<<=1){
    int u = (t>=off) ? s[t-off] : 0;
    __syncthreads();
    s[t] += u;
    __syncthreads();
  }
  int base = boff[blockIdx.x];
  if (idx < N){
    int ex = base + s[t] - v;
    rowptr[idx] = ex;
    cursor[idx] = ex;
    if (idx == N-1) rowptr[N] = base + s[t];
  }
}

__global__ void k_fill(const int* __restrict__ dst, const int* __restrict__ src,
                       int* __restrict__ cursor, int* __restrict__ inv, int* __restrict__ src_sorted, int E){
  int e = blockIdx.x*blockDim.x + threadIdx.x;
  if (e < E){
    int p = atomicAdd(&cursor[dst[e]], 1);
    inv[e] = p;
    src_sorted[p] = src[e];
  }
}

// ---------------- edge features in CSR order; y stride 10 with [8]=1,[9]=0 ----------------
__global__ void k_efeat(const float* __restrict__ pos, const int* __restrict__ src,
                        const int* __restrict__ dst, const int* __restrict__ inv,
                        float* __restrict__ rb_csr, float* __restrict__ y_csr, int E){
  int e = blockIdx.x*blockDim.x + threadIdx.x;
  if (e >= E) return;
  int s = src[e], d = dst[e];
  int j = inv[e];
  float vx = pos[d*3+0]-pos[s*3+0];
  float vy = pos[d*3+1]-pos[s*3+1];
  float vz = pos[d*3+2]-pos[s*3+2];
  float elen = sqrtf(vx*vx+vy*vy+vz*vz);
  float iv = 1.f/(elen+1e-9f);
  float x = vx*iv, y = vy*iv, zc = vz*iv;
  const float s3 = 1.7320508075688772f, s5 = 2.2360679774997896f, s15 = 3.872983346207417f;
  float* yp = y_csr + (size_t)j*10;   // Y1..Y8, [8]=1, [9]=0
  yp[0] = s3*x;  yp[1] = s3*y;  yp[2] = s3*zc;
  yp[3] = s15*x*y; yp[4] = s15*y*zc;
  yp[5] = 0.5f*s5*(3.f*zc*zc-1.f);
  yp[6] = s15*x*zc; yp[7] = 0.5f*s15*(x*x-y*y);
  yp[8] = 1.f; yp[9] = 0.f;
  const float sigma = 5.0f/9.0f;
  float* rp = rb_csr + (size_t)j*10;
  #pragma unroll
  for (int k=0;k<10;k++){
    float c = (5.0f/9.0f)*(float)k;
    float tt = (elen - c)/sigma;
    rp[k] = __expf(-0.5f*tt*tt);
  }
}

// ---------------- k_wgt: radial weights in CSR order, fp16 ----------------
__global__ __launch_bounds__(320) void k_wgt(
    const float* __restrict__ rb_csr,
    const float* __restrict__ rW1, const float* __restrict__ rb1, const float* __restrict__ rW2,
    __half* __restrict__ wgtbuf, int E, int l)
{
  __shared__ float hid[TILE_E][32];
  int t = threadIdx.x;
  int j0 = blockIdx.x*TILE_E;

  for (int idx=t; idx<TILE_E*32; idx+=320){
    int el = idx>>5, jj = idx&31;
    int j = j0+el;
    if (j < E){
      float acc = rb1[l*32+jj];
      const float* rbp = rb_csr + (size_t)j*10;
      const float* w1p = rW1 + (l*10)*32 + jj;
      #pragma unroll
      for (int k=0;k<10;k++) acc += rbp[k]*w1p[k*32];
      hid[el][jj] = silu_f(acc);
    }
  }
  float wcol[32];
  {
    const float* w2p = rW2 + (size_t)(l*32)*320 + t;
    #pragma unroll
    for (int jj=0;jj<32;jj++) wcol[jj] = w2p[(size_t)jj*320];
  }
  __syncthreads();

  for (int el=0; el<TILE_E; el++){
    int j = j0+el;
    if (j >= E) break;
    const float4* hrow = (const float4*)hid[el];
    float a0=0.f,a1=0.f,a2=0.f,a3=0.f;
    #pragma unroll
    for (int q=0;q<8;q++){
      float4 h4 = hrow[q];
      a0 += h4.x*wcol[q*4+0];
      a1 += h4.y*wcol[q*4+1];
      a2 += h4.z*wcol[q*4+2];
      a3 += h4.w*wcol[q*4+3];
    }
    wgtbuf[(size_t)j*320 + t] = __float2half((a0+a1)+(a2+a3));
  }
}

// ---------------- k_scat: (component-group, node-chunk) register aggregation ----------------
// flat comp layout c in [0,896): [0,112) a0; [112,496) a1 (row*3+dd); [496,896) a2 (row*5+dd)
__global__ __launch_bounds__(256) void k_scat(
    const float* __restrict__ H, const int* __restrict__ rowptr,
    const int* __restrict__ src_sorted, const float* __restrict__ y_csr,
    const __half* __restrict__ wgtbuf, float* __restrict__ aG, int N, int nchunks)
{
  int t = threadIdx.x, w = t>>6, lane = t&63;
  int wid = blockIdx.x*4 + w;
  if (wid >= nchunks*14) return;
  int chunk = wid/14, g = wid - chunk*14;
  int c = g*64 + lane;

  // per-lane mapping (verified R3/R4 mapping, y indices into stride-10 y_csr)
  int special = 0;     // 0: h0*ya - h1*yb ; 1: h0 ; 2: dot3 ; 3: dot5
  int widx, off0, off1 = 0, ds0 = 8, ds1 = 9;
  if (c < 64){ special = 1; widx = c; off0 = c; }
  else if (c < 96){ special = 2; widx = c; off0 = 64 + (c-64)*3; }
  else if (c < 112){ special = 3; widx = c; off0 = 160 + (c-96)*5; }
  else if (c < 496){
    int rr = c-112, row = rr/3, dd = rr - row*3;
    if (row < 64){ widx = 112+row; off0 = row; off1 = row; ds0 = dd; ds1 = 9; }
    else if (row < 96){ widx = 176+(row-64); off0 = 64+(row-64)*3+dd; off1 = off0; ds0 = 8; ds1 = 9; }
    else {
      int cc = row-96;
      int d1 = dd+1; if (d1>2) d1-=3;
      int d2 = dd+2; if (d2>2) d2-=3;
      widx = 208+cc; off0 = 64+cc*3+d1; ds0 = d2; off1 = 64+cc*3+d2; ds1 = d1;
    }
  } else {
    int rr = c-496, row = rr/5, dd = rr - row*5;
    if (row < 64){ widx = 240+row; off0 = row; off1 = row; ds0 = 3+dd; ds1 = 9; }
    else { widx = 304+(row-64); off0 = 160+(row-64)*5+dd; off1 = off0; ds0 = 8; ds1 = 9; }
  }

  int n0 = chunk*SCAT_K;
  int n1 = min(n0+SCAT_K, N);
  for (int n=n0; n<n1; n++){
    int rs = rowptr[n], re = rowptr[n+1];
    float r = 0.f;
    for (int j=rs; j<re; j++){
      int s_ = src_sorted[j];
      const float* Hs = H + (size_t)s_*240;
      const float* yj = y_csr + (size_t)j*10;
      float wg = __half2float(wgtbuf[(size_t)j*320 + widx]);
      float val;
      if (special == 1){
        val = Hs[off0];
      } else if (special == 0){
        val = Hs[off0]*yj[ds0] - Hs[off1]*yj[ds1];
      } else if (special == 2){
        val = Hs[off0]*yj[0] + Hs[off0+1]*yj[1] + Hs[off0+2]*yj[2];
      } else {
        val = Hs[off0]*yj[3] + Hs[off0+1]*yj[4] + Hs[off0+2]*yj[5]
            + Hs[off0+3]*yj[6] + Hs[off0+4]*yj[7];
      }
      r += wg*val;
    }
    aG[(size_t)n*896 + c] = r;
  }
}

// ---------------- k_upd: dense node update, in-place on H ----------------
__global__ __launch_bounds__(256) void k_upd(
    float* __restrict__ H, const float* __restrict__ aG,
    const float* __restrict__ Ws, const float* __restrict__ Wss,
    const float* __restrict__ Wv, const float* __restrict__ Wvv,
    const float* __restrict__ Wt, const float* __restrict__ Wtt,
    int N, int l)
{
  __shared__ float sA[UP_NODES][896];
  __shared__ float sH[UP_NODES][240];
  int t = threadIdx.x;
  int n0 = blockIdx.x*UP_NODES;
  int nmax = min(UP_NODES, N-n0);

  float* sAf = &sA[0][0];
  float* sHf = &sH[0][0];
  for (int idx=t; idx<nmax*896; idx+=256) sAf[idx] = aG[(size_t)n0*896 + idx];
  for (int idx=t; idx<nmax*240; idx+=256) sHf[idx] = H[(size_t)n0*240 + idx];
  __syncthreads();

  float ua[UP_NODES];
  #pragma unroll
  for (int nn=0;nn<UP_NODES;nn++) ua[nn] = 0.f;

  if (t < 64){
    int f = t;
    for (int c=0;c<112;c++){
      float wv_ = Ws[((size_t)l*112+c)*64+f];
      #pragma unroll
      for (int nn=0;nn<UP_NODES;nn++) ua[nn] += sA[nn][c]*wv_;
    }
    for (int c=0;c<64;c++){
      float wv_ = Wss[((size_t)l*64+c)*64+f];
      #pragma unroll
      for (int nn=0;nn<UP_NODES;nn++) ua[nn] += sH[nn][c]*wv_;
    }
    __syncthreads();
    for (int nn=0;nn<nmax;nn++) H[(size_t)(n0+nn)*240+f] = silu_f(ua[nn]);
  } else if (t < 160){
    int rr = t-64, f = rr/3, dd = rr - f*3;
    for (int c=0;c<128;c++){
      float wv_ = Wv[((size_t)l*128+c)*32+f];
      #pragma unroll
      for (int nn=0;nn<UP_NODES;nn++) ua[nn] += sA[nn][112+c*3+dd]*wv_;
    }
    for (int c=0;c<32;c++){
      float wv_ = Wvv[((size_t)l*32+c)*32+f];
      #pragma unroll
      for (int nn=0;nn<UP_NODES;nn++) ua[nn] += sH[nn][64+c*3+dd]*wv_;
    }
    __syncthreads();
    for (int nn=0;nn<nmax;nn++) H[(size_t)(n0+nn)*240+64+f*3+dd] = ua[nn];
  } else if (t < 240){
    int rr = t-160, f = rr/5, dd = rr - f*5;
    for (int c=0;c<80;c++){
      float wv_ = Wt[((size_t)l*80+c)*16+f];
      #pragma unroll
      for (int nn=0;nn<UP_NODES;nn++) ua[nn] += sA[nn][496+c*5+dd]*wv_;
    }
    for (int c=0;c<16;c++){
      float wv_ = Wtt[((size_t)l*16+c)*16+f];
      #pragma unroll
      for (int nn=0;nn<UP_NODES;nn++) ua[nn] += sH[nn][160+c*5+dd]*wv_;
    }
    __syncthreads();
    for (int nn=0;nn<nmax;nn++) H[(size_t)(n0+nn)*240+160+f*5+dd] = ua[nn];
  } else {
    __syncthreads();
  }
}

// ---------------- readout (H layout) ----------------
__global__ __launch_bounds__(64) void k_q(const float* __restrict__ H, const int* __restrict__ absorber,
                                          const float* __restrict__ Wq, float* __restrict__ qbuf, int G){
  __shared__ float sH[64];
  int g = blockIdx.x, f = threadIdx.x;
  int a = absorber[g];
  sH[f] = H[(size_t)a*240+f];
  __syncthreads();
  float acc = 0.f;
  for (int c=0;c<64;c++) acc += sH[c]*Wq[c*64+f];
  qbuf[(size_t)g*64+f] = acc;
}

__global__ __launch_bounds__(64) void k_kv(const float* __restrict__ H,
                                           const float* __restrict__ Wk, const float* __restrict__ Wvp,
                                           float* __restrict__ kbuf, float* __restrict__ vbuf, int N){
  __shared__ float sH[8][64];
  int t = threadIdx.x;
  int n0 = blockIdx.x*8;
  int nmax = min(8, N-n0);
  for (int idx=t; idx<nmax*64; idx+=64){ int n=idx>>6, c=idx&63; sH[n][c]=H[(size_t)(n0+n)*240+c]; }
  __syncthreads();
  float ka[8], va[8];
  #pragma unroll
  for (int n=0;n<8;n++){ ka[n]=0.f; va[n]=0.f; }
  for (int c=0;c<64;c++){
    float wk = Wk[c*64+t], wv = Wvp[c*64+t];
    #pragma unroll
    for (int n=0;n<8;n++){ ka[n]+=sH[n][c]*wk; va[n]+=sH[n][c]*wv; }
  }
  for (int n=0;n<nmax;n++){ kbuf[(size_t)(n0+n)*64+t]=ka[n]; vbuf[(size_t)(n0+n)*64+t]=va[n]; }
}

__global__ __launch_bounds__(256) void k_logit(const float* __restrict__ kbuf, const float* __restrict__ qbuf,
                                               const int* __restrict__ batch,
                                               float* __restrict__ logitbuf, unsigned* __restrict__ mkey, int N){
  int wave = threadIdx.x>>6, lane = threadIdx.x&63;
  int n = blockIdx.x*4 + wave;
  if (n >= N) return;
  int g = batch[n];
  float p = kbuf[(size_t)n*64+lane]*qbuf[(size_t)g*64+lane];
  #pragma unroll
  for (int off=32; off>0; off>>=1) p += __shfl_down(p, off, 64);
  if (lane==0){
    float logit = p*0.125f;
    logitbuf[n] = logit;
    unsigned u = __float_as_uint(logit);
    unsigned key = (u & 0x80000000u) ? ~u : (u | 0x80000000u);
    atomicMax(&mkey[g], key);
  }
}

__global__ __launch_bounds__(256) void k_soft(const float* __restrict__ vbuf, const float* __restrict__ logitbuf,
                                              const int* __restrict__ batch, const unsigned* __restrict__ mkey,
                                              float* __restrict__ den, float* __restrict__ cbuf, int N){
  int wave = threadIdx.x>>6, lane = threadIdx.x&63;
  int n = blockIdx.x*4 + wave;
  if (n >= N) return;
  int g = batch[n];
  unsigned key = mkey[g];
  unsigned u = (key & 0x80000000u) ? (key ^ 0x80000000u) : ~key;
  float m = __uint_as_float(u);
  float ex = __expf(logitbuf[n] - m);
  if (lane==0) atomicAdd(&den[g], ex);
  atomicAdd(&cbuf[(size_t)g*64+lane], ex*vbuf[(size_t)n*64+lane]);
}

__global__ __launch_bounds__(192) void k_final(const float* __restrict__ H, const int* __restrict__ absorber,
                                               const float* __restrict__ den, const float* __restrict__ cbuf,
                                               const float* __restrict__ Wr1, const float* __restrict__ br1,
                                               const float* __restrict__ Wr2, const float* __restrict__ br2,
                                               float* __restrict__ out, int G){
  __shared__ float zr[176];
  __shared__ float h1[128];
  int g = blockIdx.x, t = threadIdx.x;
  int a = absorber[g];
  if (t < 64) zr[t] = H[(size_t)a*240+t];
  else if (t < 128){
    int f = t-64;
    zr[t] = cbuf[(size_t)g*64+f] / fmaxf(den[g], 1e-9f);
  } else if (t < 160){
    int j = t-128; float s = 0.f;
    #pragma unroll
    for (int dd=0;dd<3;dd++){ float v = H[(size_t)a*240+64+j*3+dd]; s += v*v; }
    zr[t] = s;
  } else if (t < 176){
    int j = t-160; float s = 0.f;
    #pragma unroll
    for (int dd=0;dd<5;dd++){ float v = H[(size_t)a*240+160+j*5+dd]; s += v*v; }
    zr[t] = s;
  }
  __syncthreads();
  if (t < 128){
    float acc = br1[t];
    for (int i=0;i<176;i++) acc += zr[i]*Wr1[i*128+t];
    h1[t] = silu_f(acc);
  }
  __syncthreads();
  if (t < 128){
    float acc = br2[t];
    for (int j=0;j<128;j++) acc += h1[j]*Wr2[j*128+t];
    out[(size_t)g*128+t] = acc;
  }
}

extern "C" void kernel_launch(void* const* d_in, const int* in_sizes, int n_in,
                              void* d_out, int out_size, void* d_ws, size_t ws_size,
                              hipStream_t stream){
  const int*   z        = (const int*)  d_in[0];
  const float* pos      = (const float*)d_in[1];
  const int*   ei       = (const int*)  d_in[2];
  const int*   batch    = (const int*)  d_in[3];
  const int*   absorber = (const int*)  d_in[4];
  const float* embed    = (const float*)d_in[5];
  const float* rW1      = (const float*)d_in[6];
  const float* rb1      = (const float*)d_in[7];
  const float* rW2      = (const float*)d_in[8];
  const float* Ws       = (const float*)d_in[9];
  const float* Wss      = (const float*)d_in[10];
  const float* Wv       = (const float*)d_in[11];
  const float* Wvv      = (const float*)d_in[12];
  const float* Wt       = (const float*)d_in[13];
  const float* Wtt      = (const float*)d_in[14];
  const float* Wq       = (const float*)d_in[15];
  const float* Wk       = (const float*)d_in[16];
  const float* Wvp      = (const float*)d_in[17];
  const float* Wr1      = (const float*)d_in[18];
  const float* br1      = (const float*)d_in[19];
  const float* Wr2      = (const float*)d_in[20];
  const float* br2      = (const float*)d_in[21];

  int N = in_sizes[0];
  int E = in_sizes[2]/2;
  int G = in_sizes[4];
  const int* srcArr = ei;
  const int* dstArr = ei + E;

  float* p = (float*)d_ws;
  float* H     = p; p += (size_t)N*240;
  float* rb_csr= p; p += (size_t)E*10;
  float* y_csr = p; p += (size_t)E*10;
  unsigned* mkey = (unsigned*)p; p += G;
  float* den   = p; p += G;
  float* cbuf  = p; p += (size_t)G*64;
  int* deg     = (int*)p; p += N;
  int* rowptr  = (int*)p; p += (N+1);
  int* cursor  = (int*)p; p += N;
  int* inv     = (int*)p; p += E;
  int* src_sorted = (int*)p; p += E;
  int* bsum    = (int*)p; p += 256;
  int* boff    = (int*)p; p += 256;
  p += ((8 - (((uintptr_t)p >> 2) & 7)) & 7);   // 32B align
  __half* wgtbuf = (__half*)p; p += (size_t)E*160;   // E*320 halfs
  float* aG    = p; p += (size_t)N*896;
  // readout buffers alias aG (dead after last k_upd)
  float* kbuf    = aG;
  float* vbuf    = kbuf + (size_t)N*64;
  float* qbuf    = vbuf + (size_t)N*64;
  float* logitbuf= qbuf + (size_t)G*64;

  int nb = (N + 255)/256;
  int nchunks = (N + SCAT_K - 1)/SCAT_K;
  int scat_waves = nchunks*14;
  int scat_blocks = (scat_waves + 3)/4;

  k_init<<<((size_t)N*240+255)/256, 256, 0, stream>>>(z, embed, H, deg, mkey, den, cbuf, N, G);
  k_deg<<<(E+255)/256, 256, 0, stream>>>(dstArr, deg, E);
  k_scanA<<<nb, 256, 0, stream>>>(deg, bsum, N);
  k_scanB<<<1, 256, 0, stream>>>(bsum, boff, nb);
  k_scanC<<<nb, 256, 0, stream>>>(deg, boff, rowptr, cursor, N);
  k_fill<<<(E+255)/256, 256, 0, stream>>>(dstArr, srcArr, cursor, inv, src_sorted, E);
  k_efeat<<<(E+255)/256, 256, 0, stream>>>(pos, srcArr, dstArr, inv, rb_csr, y_csr, E);

  for (int l=0; l<NLAYERS; l++){
    k_wgt<<<(E+TILE_E-1)/TILE_E, 320, 0, stream>>>(rb_csr, rW1, rb1, rW2, wgtbuf, E, l);
    k_scat<<<scat_blocks, 256, 0, stream>>>(H, rowptr, src_sorted, y_csr, wgtbuf, aG, N, nchunks);
    k_upd<<<(N+UP_NODES-1)/UP_NODES, 256, 0, stream>>>(H, aG, Ws, Wss, Wv, Wvv, Wt, Wtt, N, l);
  }

  k_q<<<G, 64, 0, stream>>>(H, absorber, Wq, qbuf, G);
  k_kv<<<(N+7)/8, 64, 0, stream>>>(H, Wk, Wvp, kbuf, vbuf, N);
  k_logit<<<(N+3)/4, 256, 0, stream>>>(kbuf, qbuf, batch, logitbuf, mkey, N);
  k_soft<<<(N+3)/4, 256, 0, stream>>>(vbuf, logitbuf, batch, mkey, den, cbuf, N);
  k_final<<<G, 192, 0, stream>>>(H, absorber, den, cbuf, Wr1, br1, Wr2, br2, (float*)d_out, G);
}